// Round 2
// baseline (866.679 us; speedup 1.0000x reference)
//
#include <hip/hip_runtime.h>

#define N_ 4
#define D_ 16
#define H_ 112
#define W_ 112
#define C_ 64

#define DO_ 2
#define HO_ 2
#define DT_ (D_ / DO_)                     // 8 d-tiles
#define HTILES (H_ / HO_)                  // 56 h-tiles
#define WAVES_PER_BLOCK 4
#define HGROUPS (HTILES / WAVES_PER_BLOCK) // 14
#define WSPLIT 4
#define WQ (W_ / WSPLIT)                   // 28 output cols/wave -> 30 steps = 5*6
#define NWG (N_ * DT_ * HGROUPS * WSPLIT)  // 1792 blocks
#define CB (C_ * 4)                        // 256 B per w-column per lane-channel

// Zero page for SAME-padding halo rows (.bss = zero-initialized, never written).
__device__ float zpage[W_ * C_];

// Accumulate-forward depthwise conv step: input column ci scatters into the 3
// live output-column accumulator sets: N = col ci+1 (kw=0), M = ci (kw=1),
// O = ci-1 (kw=2). KWM bitmask {1=N,2=M,4=O} drops contributions to boundary
// columns owned by neighbor waves. All indices compile-time -> guaranteed VGPRs.
template <int U, int DR, int HR, int KWM>
__device__ __forceinline__ void stream_fma(float (&acc)[3][2][2],
                                           const float (&wt)[3][3][3],
                                           float v) {
  constexpr int iN = U % 3;
  constexpr int iM = (U + 5) % 3;   // (U-1) mod 3
  constexpr int iO = (U + 4) % 3;   // (U-2) mod 3
#pragma unroll
  for (int od = (DR >= 2 ? DR - 2 : 0); od <= (DR < 1 ? DR : 1); ++od)
#pragma unroll
    for (int oh = (HR >= 2 ? HR - 2 : 0); oh <= (HR < 1 ? HR : 1); ++oh) {
      if (KWM & 1) acc[iN][od][oh] += v * wt[DR - od][HR - oh][0];
      if (KWM & 2) acc[iM][od][oh] += v * wt[DR - od][HR - oh][1];
      if (KWM & 4) acc[iO][od][oh] += v * wt[DR - od][HR - oh][2];
    }
}

// FMA burst for one stream, then immediately reuse its pf reg for the next
// column's load (single-buffer prefetch: issue-after-last-use, consume next step)
#define FL(U, M, DR, HR)                                        \
  stream_fma<U, DR, HR, M>(acc, wt, pf[DR][HR]);                \
  pf[DR][HR] = *(const float*)(bx[DR][HR] + vb);
#define F_(U, M, DR, HR) stream_fma<U, DR, HR, M>(acc, wt, pf[DR][HR]);
#define L_(DR, HR) pf[DR][HR] = *(const float*)(bx[DR][HR] + vb);

#define FMA_LOAD_ALL(U, M)                                      \
  FL(U,M,0,0) FL(U,M,0,1) FL(U,M,0,2) FL(U,M,0,3)               \
  FL(U,M,1,0) FL(U,M,1,1) FL(U,M,1,2) FL(U,M,1,3)               \
  FL(U,M,2,0) FL(U,M,2,1) FL(U,M,2,2) FL(U,M,2,3)               \
  FL(U,M,3,0) FL(U,M,3,1) FL(U,M,3,2) FL(U,M,3,3)

#define FMA_ALL(U, M)                                           \
  F_(U,M,0,0) F_(U,M,0,1) F_(U,M,0,2) F_(U,M,0,3)               \
  F_(U,M,1,0) F_(U,M,1,1) F_(U,M,1,2) F_(U,M,1,3)               \
  F_(U,M,2,0) F_(U,M,2,1) F_(U,M,2,2) F_(U,M,2,3)               \
  F_(U,M,3,0) F_(U,M,3,1) F_(U,M,3,2) F_(U,M,3,3)

#define LOAD_ALL()                                              \
  L_(0,0) L_(0,1) L_(0,2) L_(0,3) L_(1,0) L_(1,1) L_(1,2) L_(1,3) \
  L_(2,0) L_(2,1) L_(2,2) L_(2,3) L_(3,0) L_(3,1) L_(3,2) L_(3,3)

// store completed O set (output col = current vb col - 2) and re-zero it; the
// zeroed set becomes next step's N set.
#define STORE4(U)                                                             \
  *(float*)(ox[0][0] + (vb - 2*CB)) = acc[(U+4)%3][0][0]; acc[(U+4)%3][0][0] = 0.f; \
  *(float*)(ox[0][1] + (vb - 2*CB)) = acc[(U+4)%3][0][1]; acc[(U+4)%3][0][1] = 0.f; \
  *(float*)(ox[1][0] + (vb - 2*CB)) = acc[(U+4)%3][1][0]; acc[(U+4)%3][1][0] = 0.f; \
  *(float*)(ox[1][1] + (vb - 2*CB)) = acc[(U+4)%3][1][1]; acc[(U+4)%3][1][1] = 0.f;

__global__ __launch_bounds__(256, 8)   // pin allocator at 64 VGPR -> 8 blocks/CU
void dwconv3d_kernel(const float* __restrict__ x,
                     const float* __restrict__ wgt,
                     float* __restrict__ out) {
    // bijective XCD-aware swizzle (NWG % 8 == 0)
    int b = blockIdx.x;
    b = (b & 7) * (NWG / 8) + (b >> 3);
    const int wh = b % WSPLIT; b /= WSPLIT;
    const int hg = b % HGROUPS; b /= HGROUPS;
    const int dt = b % DT_;     b /= DT_;
    const int n  = b;

    const int c   = threadIdx.x & 63;
    const int wid = __builtin_amdgcn_readfirstlane(threadIdx.x >> 6);

    const int d0 = dt * DO_;
    const int h0 = (hg * WAVES_PER_BLOCK + wid) * HO_;
    const int w0 = wh * WQ;

    // per-lane weights (27 VGPRs), coalesced
    float wt[3][3][3];
#pragma unroll
    for (int kd = 0; kd < 3; ++kd)
#pragma unroll
      for (int kh = 0; kh < 3; ++kh)
#pragma unroll
        for (int kw = 0; kw < 3; ++kw)
          wt[kd][kh][kw] = wgt[((kd * 3 + kh) * 3 + kw) * C_ + c];

    // 16 wave-uniform stream bases (SGPR pairs): x row (d,h) or the zero page
    const char* bx[4][4];
#pragma unroll
    for (int dr = 0; dr < 4; ++dr) {
      const int d = d0 - 1 + dr;
#pragma unroll
      for (int hr = 0; hr < 4; ++hr) {
        const int h = h0 - 1 + hr;
        if (d >= 0 && d < D_ && h >= 0 && h < H_)
          bx[dr][hr] = (const char*)(x + (size_t)((n * D_ + d) * H_ + h) * W_ * C_);
        else
          bx[dr][hr] = (const char*)zpage;
      }
    }

    // 4 wave-uniform output row bases
    char* ox[2][2];
#pragma unroll
    for (int od = 0; od < 2; ++od)
#pragma unroll
      for (int oh = 0; oh < 2; ++oh)
        ox[od][oh] = (char*)(out +
            (size_t)((n * D_ + d0 + od) * H_ + (h0 + oh)) * W_ * C_);

    float pf[4][4];          // current input column (single-buffer prefetch)
    float acc[3][2][2];      // 3 output-column partial sets x 2x2 (d,h) outputs
#pragma unroll
    for (int i = 0; i < 3; ++i)
#pragma unroll
      for (int od = 0; od < 2; ++od)
#pragma unroll
        for (int oh = 0; oh < 2; ++oh) acc[i][od][oh] = 0.f;

    // at step s: vb = byte offset of prefetch col (w0+s); FMA col = w0-1+s;
    // store col = w0+s-2 (offset vb - 2*CB)
    unsigned vb = (unsigned)(w0 * CB) + (unsigned)(c * 4);
    const bool wend = (w0 + WQ < W_);   // wh < WSPLIT-1

    // ---- s=0: consume col w0-1 (only N target = our col w0), prefetch col w0
    if (w0) {
#pragma unroll
      for (int dr = 0; dr < 4; ++dr)
#pragma unroll
        for (int hr = 0; hr < 4; ++hr)
          pf[dr][hr] = *(const float*)(bx[dr][hr] + (vb - CB));
      FMA_LOAD_ALL(0, 1)
    } else {
      LOAD_ALL()             // col -1 is all zeros: no FMAs at all
    }
    vb += CB;
    // ---- s=1: cols w0 -> targets {w0, w0+1} (N|M); no store yet
    FMA_LOAD_ALL(1, 3) vb += CB;
    // ---- s=2..5
    FMA_LOAD_ALL(2, 7) STORE4(2) vb += CB;
    FMA_LOAD_ALL(3, 7) STORE4(3) vb += CB;
    FMA_LOAD_ALL(4, 7) STORE4(4) vb += CB;
    FMA_LOAD_ALL(5, 7) STORE4(5) vb += CB;
    // ---- s=6..23: three clean 6-step blocks (acc period 3 | 6, pf period 1)
#pragma unroll 1
    for (int it = 0; it < 3; ++it) {
      FMA_LOAD_ALL(0, 7) STORE4(0) vb += CB;
      FMA_LOAD_ALL(1, 7) STORE4(1) vb += CB;
      FMA_LOAD_ALL(2, 7) STORE4(2) vb += CB;
      FMA_LOAD_ALL(3, 7) STORE4(3) vb += CB;
      FMA_LOAD_ALL(4, 7) STORE4(4) vb += CB;
      FMA_LOAD_ALL(5, 7) STORE4(5) vb += CB;
    }
    // ---- s=24..27
    FMA_LOAD_ALL(0, 7) STORE4(0) vb += CB;
    FMA_LOAD_ALL(1, 7) STORE4(1) vb += CB;
    FMA_LOAD_ALL(2, 7) STORE4(2) vb += CB;
    FMA_LOAD_ALL(3, 7) STORE4(3) vb += CB;
    // ---- s=28: N target (col w0+28) is neighbor's -> mask M|O; prefetch col
    // w0+28 only if it exists (it's this wave's last input column)
    if (wend) {
      FMA_LOAD_ALL(4, 6)
    } else {
      FMA_ALL(4, 6)
    }
    STORE4(4) vb += CB;
    // ---- s=29: input col w0+28 (exists iff wend, already in pf); only O
    // target (our last output col w0+27) kept
    if (wend) { FMA_ALL(5, 4) }
    STORE4(5)
}

extern "C" void kernel_launch(void* const* d_in, const int* in_sizes, int n_in,
                              void* d_out, int out_size, void* d_ws, size_t ws_size,
                              hipStream_t stream) {
    const float* x   = (const float*)d_in[0];
    const float* wgt = (const float*)d_in[1];
    float* out = (float*)d_out;

    dim3 grid(NWG);   // 1792 blocks = 7168 waves = 28 waves/CU of work
    dim3 block(256);
    dwconv3d_kernel<<<grid, block, 0, stream>>>(x, wgt, out);
}

// Round 3
// 370.830 us; speedup vs baseline: 2.3371x; 2.3371x over previous
//
#include <hip/hip_runtime.h>

#define N_ 4
#define D_ 16
#define H_ 112
#define W_ 112
#define C_ 64

#define DO_ 2
#define HO_ 2
#define DT_ (D_ / DO_)                     // 8 d-tiles
#define HTILES (H_ / HO_)                  // 56 h-tiles
#define WAVES_PER_BLOCK 4
#define HGROUPS (HTILES / WAVES_PER_BLOCK) // 14
#define WSPLIT 4
#define WQ (W_ / WSPLIT)                   // 28 output cols/wave -> 30 steps = 5*6
#define NWG (N_ * DT_ * HGROUPS * WSPLIT)  // 1792 blocks
#define CB (C_ * 4)                        // 256 B per w-column per lane-channel

// Zero page for SAME-padding halo rows (.bss = zero-initialized, never written).
__device__ float zpage[W_ * C_];

// Accumulate-forward depthwise conv step: input column ci scatters into the 3
// live output-column accumulator sets: N = col ci+1 (kw=0), M = ci (kw=1),
// O = ci-1 (kw=2). KWM bitmask {1=N,2=M,4=O} drops contributions to boundary
// columns owned by neighbor waves. All indices compile-time -> guaranteed VGPRs.
// Live set: 27 wt + 12 acc + 16 pf + addressing ~= 65 -> needs >=85 reg budget.
template <int U, int DR, int HR, int KWM>
__device__ __forceinline__ void stream_fma(float (&acc)[3][2][2],
                                           const float (&wt)[3][3][3],
                                           float v) {
  constexpr int iN = U % 3;
  constexpr int iM = (U + 5) % 3;   // (U-1) mod 3
  constexpr int iO = (U + 4) % 3;   // (U-2) mod 3
#pragma unroll
  for (int od = (DR >= 2 ? DR - 2 : 0); od <= (DR < 1 ? DR : 1); ++od)
#pragma unroll
    for (int oh = (HR >= 2 ? HR - 2 : 0); oh <= (HR < 1 ? HR : 1); ++oh) {
      if (KWM & 1) acc[iN][od][oh] += v * wt[DR - od][HR - oh][0];
      if (KWM & 2) acc[iM][od][oh] += v * wt[DR - od][HR - oh][1];
      if (KWM & 4) acc[iO][od][oh] += v * wt[DR - od][HR - oh][2];
    }
}

// FMA burst for one stream, then immediately reuse its pf reg for the next
// column's load (single-buffer prefetch: issue-after-last-use, consume next step)
#define FL(U, M, DR, HR)                                        \
  stream_fma<U, DR, HR, M>(acc, wt, pf[DR][HR]);                \
  pf[DR][HR] = *(const float*)(bx[DR][HR] + vb);
#define F_(U, M, DR, HR) stream_fma<U, DR, HR, M>(acc, wt, pf[DR][HR]);
#define L_(DR, HR) pf[DR][HR] = *(const float*)(bx[DR][HR] + vb);

#define FMA_LOAD_ALL(U, M)                                      \
  FL(U,M,0,0) FL(U,M,0,1) FL(U,M,0,2) FL(U,M,0,3)               \
  FL(U,M,1,0) FL(U,M,1,1) FL(U,M,1,2) FL(U,M,1,3)               \
  FL(U,M,2,0) FL(U,M,2,1) FL(U,M,2,2) FL(U,M,2,3)               \
  FL(U,M,3,0) FL(U,M,3,1) FL(U,M,3,2) FL(U,M,3,3)

#define FMA_ALL(U, M)                                           \
  F_(U,M,0,0) F_(U,M,0,1) F_(U,M,0,2) F_(U,M,0,3)               \
  F_(U,M,1,0) F_(U,M,1,1) F_(U,M,1,2) F_(U,M,1,3)               \
  F_(U,M,2,0) F_(U,M,2,1) F_(U,M,2,2) F_(U,M,2,3)               \
  F_(U,M,3,0) F_(U,M,3,1) F_(U,M,3,2) F_(U,M,3,3)

#define LOAD_ALL()                                              \
  L_(0,0) L_(0,1) L_(0,2) L_(0,3) L_(1,0) L_(1,1) L_(1,2) L_(1,3) \
  L_(2,0) L_(2,1) L_(2,2) L_(2,3) L_(3,0) L_(3,1) L_(3,2) L_(3,3)

// store completed O set (output col = current vb col - 2) and re-zero it; the
// zeroed set becomes next step's N set.
#define STORE4(U)                                                             \
  *(float*)(ox[0][0] + (vb - 2*CB)) = acc[(U+4)%3][0][0]; acc[(U+4)%3][0][0] = 0.f; \
  *(float*)(ox[0][1] + (vb - 2*CB)) = acc[(U+4)%3][0][1]; acc[(U+4)%3][0][1] = 0.f; \
  *(float*)(ox[1][0] + (vb - 2*CB)) = acc[(U+4)%3][1][0]; acc[(U+4)%3][1][0] = 0.f; \
  *(float*)(ox[1][1] + (vb - 2*CB)) = acc[(U+4)%3][1][1]; acc[(U+4)%3][1][1] = 0.f;

// (256,4): VGPR cap 128. Round-2's (256,8) pinned the ~65-value live set into a
// 64-reg budget -> catastrophic scratch spill (FETCH 1.4GB, WRITE 847MB, 645us).
// Never pin below live-set + scheduling margin.
__global__ __launch_bounds__(256, 4)
void dwconv3d_kernel(const float* __restrict__ x,
                     const float* __restrict__ wgt,
                     float* __restrict__ out) {
    // bijective XCD-aware swizzle (NWG % 8 == 0)
    int b = blockIdx.x;
    b = (b & 7) * (NWG / 8) + (b >> 3);
    const int wh = b % WSPLIT; b /= WSPLIT;
    const int hg = b % HGROUPS; b /= HGROUPS;
    const int dt = b % DT_;     b /= DT_;
    const int n  = b;

    const int c   = threadIdx.x & 63;
    const int wid = __builtin_amdgcn_readfirstlane(threadIdx.x >> 6);

    const int d0 = dt * DO_;
    const int h0 = (hg * WAVES_PER_BLOCK + wid) * HO_;
    const int w0 = wh * WQ;

    // per-lane weights (27 VGPRs), coalesced
    float wt[3][3][3];
#pragma unroll
    for (int kd = 0; kd < 3; ++kd)
#pragma unroll
      for (int kh = 0; kh < 3; ++kh)
#pragma unroll
        for (int kw = 0; kw < 3; ++kw)
          wt[kd][kh][kw] = wgt[((kd * 3 + kh) * 3 + kw) * C_ + c];

    // 16 wave-uniform stream bases (SGPR pairs): x row (d,h) or the zero page
    const char* bx[4][4];
#pragma unroll
    for (int dr = 0; dr < 4; ++dr) {
      const int d = d0 - 1 + dr;
#pragma unroll
      for (int hr = 0; hr < 4; ++hr) {
        const int h = h0 - 1 + hr;
        if (d >= 0 && d < D_ && h >= 0 && h < H_)
          bx[dr][hr] = (const char*)(x + (size_t)((n * D_ + d) * H_ + h) * W_ * C_);
        else
          bx[dr][hr] = (const char*)zpage;
      }
    }

    // 4 wave-uniform output row bases
    char* ox[2][2];
#pragma unroll
    for (int od = 0; od < 2; ++od)
#pragma unroll
      for (int oh = 0; oh < 2; ++oh)
        ox[od][oh] = (char*)(out +
            (size_t)((n * D_ + d0 + od) * H_ + (h0 + oh)) * W_ * C_);

    float pf[4][4];          // current input column (single-buffer prefetch)
    float acc[3][2][2];      // 3 output-column partial sets x 2x2 (d,h) outputs
#pragma unroll
    for (int i = 0; i < 3; ++i)
#pragma unroll
      for (int od = 0; od < 2; ++od)
#pragma unroll
        for (int oh = 0; oh < 2; ++oh) acc[i][od][oh] = 0.f;

    // at step s: vb = byte offset of prefetch col (w0+s); FMA col = w0-1+s;
    // store col = w0+s-2 (offset vb - 2*CB)
    unsigned vb = (unsigned)(w0 * CB) + (unsigned)(c * 4);
    const bool wend = (w0 + WQ < W_);   // wh < WSPLIT-1 (block-uniform)

    // ---- s=0: consume col w0-1 (only N target = our col w0), prefetch col w0
    if (w0) {
#pragma unroll
      for (int dr = 0; dr < 4; ++dr)
#pragma unroll
        for (int hr = 0; hr < 4; ++hr)
          pf[dr][hr] = *(const float*)(bx[dr][hr] + (vb - CB));
      FMA_LOAD_ALL(0, 1)
    } else {
      LOAD_ALL()             // col -1 is all zeros: no FMAs at all
    }
    vb += CB;
    // ---- s=1: cols w0 -> targets {w0, w0+1} (N|M); no store yet
    FMA_LOAD_ALL(1, 3) vb += CB;
    // ---- s=2..5
    FMA_LOAD_ALL(2, 7) STORE4(2) vb += CB;
    FMA_LOAD_ALL(3, 7) STORE4(3) vb += CB;
    FMA_LOAD_ALL(4, 7) STORE4(4) vb += CB;
    FMA_LOAD_ALL(5, 7) STORE4(5) vb += CB;
    // ---- s=6..23: three clean 6-step blocks (acc period 3 | 6, pf period 1)
#pragma unroll 1
    for (int it = 0; it < 3; ++it) {
      FMA_LOAD_ALL(0, 7) STORE4(0) vb += CB;
      FMA_LOAD_ALL(1, 7) STORE4(1) vb += CB;
      FMA_LOAD_ALL(2, 7) STORE4(2) vb += CB;
      FMA_LOAD_ALL(3, 7) STORE4(3) vb += CB;
      FMA_LOAD_ALL(4, 7) STORE4(4) vb += CB;
      FMA_LOAD_ALL(5, 7) STORE4(5) vb += CB;
    }
    // ---- s=24..27
    FMA_LOAD_ALL(0, 7) STORE4(0) vb += CB;
    FMA_LOAD_ALL(1, 7) STORE4(1) vb += CB;
    FMA_LOAD_ALL(2, 7) STORE4(2) vb += CB;
    FMA_LOAD_ALL(3, 7) STORE4(3) vb += CB;
    // ---- s=28: N target (col w0+28) is neighbor's -> mask M|O; prefetch col
    // w0+28 only if it exists (it's this wave's last input column)
    if (wend) {
      FMA_LOAD_ALL(4, 6)
    } else {
      FMA_ALL(4, 6)
    }
    STORE4(4) vb += CB;
    // ---- s=29: input col w0+28 (exists iff wend, already in pf); only O
    // target (our last output col w0+27) kept
    if (wend) { FMA_ALL(5, 4) }
    STORE4(5)
}

extern "C" void kernel_launch(void* const* d_in, const int* in_sizes, int n_in,
                              void* d_out, int out_size, void* d_ws, size_t ws_size,
                              hipStream_t stream) {
    const float* x   = (const float*)d_in[0];
    const float* wgt = (const float*)d_in[1];
    float* out = (float*)d_out;

    dim3 grid(NWG);   // 1792 blocks = 7168 waves = 28 waves/CU of work
    dim3 block(256);
    dwconv3d_kernel<<<grid, block, 0, stream>>>(x, wgt, out);
}